// Round 21
// baseline (87.366 us; speedup 1.0000x reference)
//
#include <hip/hip_runtime.h>
#include <math.h>
#include <float.h>

// Problem constants (from reference)
#define NPT     16384
#define IN_F    34
#define SDIM    4
#define PDIM    22
#define KNN     8
#define WIDTH   126
#define WPAD    128    // padded width for conflict-free LDS
#define NCLS    6
#define ROWS    16     // rows per fused-MLP block (256 threads)

typedef unsigned long long u64;

// ---------------- workspace layout (bytes), total ~3 MB ----------------
#define OFF_RANGES 0
#define OFF_S      256
#define OFF_H      (OFF_S  + NPT*SDIM*4)
#define OFF_KIDX   (OFF_H  + NPT*PDIM*4)
#define OFF_KW     (OFF_KIDX + NPT*KNN*4)

// key bits = (float_bits(d2) << 32) | j : u64 order == lex (d2, idx) order ==
// jax.lax.top_k tie-breaking. d2 >= 0 -> the f64 view is positive, never
// NaN/Inf -> IEEE f64 order == unsigned bit order -> networks run on
// v_min_f64/v_max_f64 (CE = 2 instr vs 5 for u64).
#define INITK_BITS 0x7f7fffffffffffffULL

__device__ __forceinline__ void ce(double& a, double& b) {   // a=min, b=max
    double mn = __builtin_fmin(a, b);
    double mx = __builtin_fmax(a, b);
    a = mn; b = mx;
}
__device__ __forceinline__ double dmin64(double a, double b) {
    return __builtin_fmin(a, b);
}
__device__ __forceinline__ double pack_key(float d2, unsigned j) {
    return __longlong_as_double((long long)(((u64)__float_as_uint(d2) << 32) | j));
}

__device__ __forceinline__ void key_insert(double key, double* u) {
#pragma unroll
    for (int t = 0; t < KNN; ++t) {
        double mn = __builtin_fmin(key, u[t]);
        double mx = __builtin_fmax(key, u[t]);
        u[t] = mn;
        key  = mx;
    }
}

// lgkm-only barrier: waits LDS ops, leaves global prefetch loads in flight.
__device__ __forceinline__ void lgkm_barrier() {
    asm volatile("s_waitcnt lgkmcnt(0)" ::: "memory");
    __builtin_amdgcn_s_barrier();
    asm volatile("" ::: "memory");
}

// match reference numerics: rounded squares, sequential sum, no fma
__device__ __forceinline__ float dist2(const float4 a, const float4 b) {
    float d0 = a.x - b.x;
    float d1 = a.y - b.y;
    float d2 = a.z - b.z;
    float d3 = a.w - b.w;
    return __fadd_rn(__fadd_rn(__fadd_rn(__fmul_rn(d0, d0),
                                         __fmul_rn(d1, d1)),
                               __fmul_rn(d2, d2)),
                     __fmul_rn(d3, d3));
}

// 12-CE bitonic sort of a bitonic 8-sequence (m0..m7), ascending result
#define BITONIC8(m0,m1,m2,m3,m4,m5,m6,m7) \
    ce(m0,m4); ce(m1,m5); ce(m2,m6); ce(m3,m7); \
    ce(m0,m2); ce(m1,m3); ce(m4,m6); ce(m5,m7); \
    ce(m0,m1); ce(m2,m3); ce(m4,m5); ce(m6,m7);

// Batcher odd-even mergesort network for 8 keys (19 CE), ascending
#define SORT8(k0,k1,k2,k3,k4,k5,k6,k7) \
    ce(k0,k1); ce(k2,k3); ce(k4,k5); ce(k6,k7); \
    ce(k0,k2); ce(k1,k3); ce(k4,k6); ce(k5,k7); \
    ce(k1,k2); ce(k5,k6); \
    ce(k0,k4); ce(k1,k5); ce(k2,k6); ce(k3,k7); \
    ce(k2,k4); ce(k3,k5); \
    ce(k1,k2); ce(k3,k4); ce(k5,k6);

// ---------------------------------------------------------
// s = (x@Ws + bs) + 1000*batch ; h = x@Wh + bh  (conv index 1 weights).
__global__ __launch_bounds__(256) void k_sh(const float* __restrict__ x,
                                            const int* __restrict__ batch,
                                            const float* __restrict__ Ws,
                                            const float* __restrict__ bs,
                                            const float* __restrict__ Wh,
                                            const float* __restrict__ bh,
                                            float* __restrict__ S,
                                            float* __restrict__ H,
                                            int* __restrict__ ranges) {
    int t = blockIdx.x * blockDim.x + threadIdx.x;
    int i = t >> 5;
    int o = t & 31;
    if (i >= NPT) return;
    if (o == 31) {  // graph ranges from sorted batch
        int b = batch[i];
        if (i == 0 || batch[i - 1] != b) ranges[b * 2]     = i;
        if (i == NPT - 1 || batch[i + 1] != b) ranges[b * 2 + 1] = i + 1;
        return;
    }
    const float* xr = x + (size_t)i * IN_F;
    if (o < SDIM) {
        float acc = 0.f;
        for (int k = 0; k < IN_F; ++k) acc += xr[k] * Ws[k * SDIM + o];
        S[(size_t)i * SDIM + o] = (acc + bs[o]) + 1000.f * (float)batch[i];
    } else if (o < SDIM + PDIM) {
        int p = o - SDIM;
        float acc = 0.f;
        for (int k = 0; k < IN_F; ++k) acc += xr[k] * Wh[k * PDIM + p];
        H[(size_t)i * PDIM + p] = acc + bh[p];
    }
}

// Fused kNN (round-14 version, verbatim): 32 lanes/query, batch-8 Batcher
// sort + keep-low-8 bitonic merge + lane butterfly, all on f64 min/max.
__global__ __launch_bounds__(256, 4) void k_knn(const float4* __restrict__ S4,
                                                const int* __restrict__ batch,
                                                const int* __restrict__ ranges,
                                                int* __restrict__ KIDX,
                                                float* __restrict__ KW) {
    const int tid = threadIdx.x;
    const int q   = blockIdx.x * 8 + (tid >> 5);
    const int t   = tid & 31;
    const int b   = batch[q];
    const int gs  = ranges[b * 2];
    const int len = ranges[b * 2 + 1] - gs;
    const float4 sq = S4[q];

    double u[KNN];
    const double initk = __longlong_as_double((long long)INITK_BITS);
#pragma unroll
    for (int e = 0; e < KNN; ++e) u[e] = initk;

    int j = gs + t;
    int done = 0;

    const int nfull8 = len >> 8;
    for (int bb = 0; bb < nfull8; ++bb, j += 256) {
        const float4* p = S4 + j;
        float4 s0 = p[0];
        float4 s1 = p[32];
        float4 s2 = p[64];
        float4 s3 = p[96];
        float4 s4 = p[128];
        float4 s5 = p[160];
        float4 s6 = p[192];
        float4 s7 = p[224];
        double k0 = pack_key(dist2(sq, s0), (unsigned)(j));
        double k1 = pack_key(dist2(sq, s1), (unsigned)(j + 32));
        double k2 = pack_key(dist2(sq, s2), (unsigned)(j + 64));
        double k3 = pack_key(dist2(sq, s3), (unsigned)(j + 96));
        double k4 = pack_key(dist2(sq, s4), (unsigned)(j + 128));
        double k5 = pack_key(dist2(sq, s5), (unsigned)(j + 160));
        double k6 = pack_key(dist2(sq, s6), (unsigned)(j + 192));
        double k7 = pack_key(dist2(sq, s7), (unsigned)(j + 224));
        SORT8(k0, k1, k2, k3, k4, k5, k6, k7);
        double m0 = dmin64(k0, u[7]);
        double m1 = dmin64(k1, u[6]);
        double m2 = dmin64(k2, u[5]);
        double m3 = dmin64(k3, u[4]);
        double m4 = dmin64(k4, u[3]);
        double m5 = dmin64(k5, u[2]);
        double m6 = dmin64(k6, u[1]);
        double m7 = dmin64(k7, u[0]);
        BITONIC8(m0, m1, m2, m3, m4, m5, m6, m7);
        u[0] = m0; u[1] = m1; u[2] = m2; u[3] = m3;
        u[4] = m4; u[5] = m5; u[6] = m6; u[7] = m7;
    }
    done = nfull8 << 8;

    if (len - done >= 128) {
        const float4* p = S4 + j;
        float4 s0 = p[0];
        float4 s1 = p[32];
        float4 s2 = p[64];
        float4 s3 = p[96];
        double k0 = pack_key(dist2(sq, s0), (unsigned)(j));
        double k1 = pack_key(dist2(sq, s1), (unsigned)(j + 32));
        double k2 = pack_key(dist2(sq, s2), (unsigned)(j + 64));
        double k3 = pack_key(dist2(sq, s3), (unsigned)(j + 96));
        ce(k0, k1); ce(k2, k3); ce(k0, k2); ce(k1, k3); ce(k1, k2);
        double m0 = dmin64(k0, u[7]);
        double m1 = dmin64(k1, u[6]);
        double m2 = dmin64(k2, u[5]);
        double m3 = dmin64(k3, u[4]);
        double m4 = u[3], m5 = u[2], m6 = u[1], m7 = u[0];
        BITONIC8(m0, m1, m2, m3, m4, m5, m6, m7);
        u[0] = m0; u[1] = m1; u[2] = m2; u[3] = m3;
        u[4] = m4; u[5] = m5; u[6] = m6; u[7] = m7;
        done += 128;
    }

    for (int m = done + t; m < len; m += 32) {
        int jj = gs + m;
        key_insert(pack_key(dist2(sq, S4[jj]), (unsigned)jj), u);
    }

#pragma unroll
    for (int mm = 1; mm < 32; mm <<= 1) {
        double p0 = __shfl_xor(u[0], mm, 32);
        double p1 = __shfl_xor(u[1], mm, 32);
        double p2 = __shfl_xor(u[2], mm, 32);
        double p3 = __shfl_xor(u[3], mm, 32);
        double p4 = __shfl_xor(u[4], mm, 32);
        double p5 = __shfl_xor(u[5], mm, 32);
        double p6 = __shfl_xor(u[6], mm, 32);
        double p7 = __shfl_xor(u[7], mm, 32);
        double m0 = dmin64(u[0], p7);
        double m1 = dmin64(u[1], p6);
        double m2 = dmin64(u[2], p5);
        double m3 = dmin64(u[3], p4);
        double m4 = dmin64(u[4], p3);
        double m5 = dmin64(u[5], p2);
        double m6 = dmin64(u[6], p1);
        double m7 = dmin64(u[7], p0);
        BITONIC8(m0, m1, m2, m3, m4, m5, m6, m7);
        u[0] = m0; u[1] = m1; u[2] = m2; u[3] = m3;
        u[4] = m4; u[5] = m5; u[6] = m6; u[7] = m7;
    }

    if (t == 0) {
#pragma unroll
        for (int e = 0; e < KNN; ++e) {
            u64 bits = (u64)__double_as_longlong(u[e]);
            float d = __uint_as_float((unsigned)(bits >> 32));
            KIDX[(size_t)q * KNN + e] = (int)(unsigned)(bits & 0xffffffffu);
            KW[(size_t)q * KNN + e]   = expf(-10.f * d);
        }
    }
}

// Fused gather+MLP, round-21: the 4-blocks/CU experiment DONE RIGHT.
// Round-18's version spilled (launch_bounds(256,4) + 8-chunk pipeline ->
// 109MB scratch writes, 357MB fetch) and lacked the XCD swizzle. This
// version: ROWS=16 @ 256 thr, grid 1024, LDS 35.8KB -> 4 independent
// barrier-groups/CU (16 waves); plain launch_bounds(256) so the allocator
// is unconstrained (no spill); XCD swizzle lb=(bid&7)*128+(bid>>3) gives
// each XCD exactly one graph -> H + W2 L2-hot (round-19 proven).
// Verify in PMC: VGPR < 128, WRITE_SIZE ~0.4MB, FETCH ~3MB.
__global__ __launch_bounds__(256) void k_fused(
        const float* __restrict__ x,
        const float* __restrict__ H,
        const int* __restrict__ KIDX,
        const float* __restrict__ KW,
        const float* __restrict__ Wo1,
        const float* __restrict__ Wo2,
        const float* __restrict__ bo2,
        const float* __restrict__ W1,
        const float* __restrict__ b1,
        const float* __restrict__ W2,
        const float* __restrict__ b2,
        const float* __restrict__ W3,
        const float* __restrict__ b3,
        float* __restrict__ out) {
    __shared__ float xt[ROWS * IN_F];       // 16x34
    __shared__ float aggt[ROWS * 2 * PDIM]; // 16x44
    __shared__ float et[ROWS * IN_F];       // 16x34
    __shared__ float h1t[ROWS * WPAD];      // 16x128 (cols 126/127 = 0)
    __shared__ float wbuf[2 * 16 * WPAD];   // W1 rows 0..31, then W2 dbuf (16 KB)
    __shared__ float w1tail[2 * WPAD];      // W1 rows 32,33
    __shared__ float w3buf[WPAD * NCLS];    // 128x6, rows 126/127 = 0
                                            // total = 35840 B -> 4 blocks/CU

    const int tid  = threadIdx.x;
    const int r    = tid >> 4;              // gather/et mapping: row 0..15
    const int c    = tid & 15;              //                    lane 0..15
    const int p    = tid >> 5;              // h1/h2/out: row-pair 0..7
    const int cg   = tid & 31;              //            col-group 0..31
    // XCD swizzle (1024 blocks, 1024%8==0 -> bijective): XCD k gets logical
    // blocks k*128..k*128+127 = exactly one graph's 2048 rows.
    const int lb   = ((blockIdx.x & 7) << 7) | (blockIdx.x >> 3);
    const int row0 = lb * ROWS;
    const int gi   = row0 + r;
    const int rA   = 2 * p;
    const int rB   = 2 * p + 1;
    const int jc   = 4 * cg;                // 4 cols (0..124)

    // ---- staging: x, W1 (rows 0..31 -> wbuf halves, 32/33 -> tail), W3 ----
    for (int t = tid; t < ROWS * IN_F; t += 256)
        xt[t] = x[(size_t)row0 * IN_F + t];
    for (int t = tid; t < IN_F * WPAD; t += 256) {
        int k = t >> 7, j = t & 127;
        float v = (j < WIDTH) ? W1[k * WIDTH + j] : 0.f;
        if (k < 32) wbuf[(k >> 4) * (16 * WPAD) + (k & 15) * WPAD + j] = v;
        else        w1tail[(k - 32) * WPAD + j] = v;
    }
    for (int t = tid; t < WPAD * NCLS; t += 256) {
        int k = t / NCLS;
        w3buf[t] = (k < WIDTH) ? W3[t] : 0.f;
    }

    // gather + aggregate: lane c<11 handles dims {c, c+11}
    if (c < 11) {
        const int p0 = c, p1 = c + 11;
        float s0 = 0.f, s1 = 0.f;
        float m0 = -FLT_MAX, m1 = -FLT_MAX;
#pragma unroll
        for (int k = 0; k < KNN; ++k) {
            int   j = KIDX[(size_t)gi * KNN + k];
            float w = KW[(size_t)gi * KNN + k];
            const float* hr = H + (size_t)j * PDIM;
            float v0 = hr[p0] * w; s0 += v0; m0 = fmaxf(m0, v0);
            float v1 = hr[p1] * w; s1 += v1; m1 = fmaxf(m1, v1);
        }
        aggt[r * 44 + p0] = s0 * 0.125f; aggt[r * 44 + PDIM + p0] = m0;
        aggt[r * 44 + p1] = s1 * 0.125f; aggt[r * 44 + PDIM + p1] = m1;
    }
    lgkm_barrier();   // xt, W1, w3, aggt visible

    // issue W2 chunk0 (rows 0..15) loads NOW; drain under et + h1
    float rvA[8], rvB[8];
#define LOAD_CHUNK(RV, K0)                                      \
    _Pragma("unroll")                                           \
    for (int i = 0; i < 8; ++i) {                               \
        int e = i * 256 + tid, kk = e >> 7, j = e & 127;        \
        int row = (K0) + kk;                                    \
        RV[i] = (j < WIDTH && row < WIDTH)                      \
                    ? W2[(size_t)row * WIDTH + j] : 0.f;        \
    }
#define STORE_CHUNK(BUFI, RV)                                   \
    _Pragma("unroll")                                           \
    for (int i = 0; i < 8; ++i)                                 \
        wbuf[(BUFI) * 2048 + i * 256 + tid] = RV[i];

    LOAD_CHUNK(rvA, 0);

    // et = x@Wo1 + agg@Wo2 + bo2 ; 3-wide chunks, j0=min(3c,31)
    {
        const int j0 = (3 * c < 31) ? 3 * c : 31;
        float acc[3] = {0.f, 0.f, 0.f};
        const float* ar = xt + r * IN_F;
#pragma unroll 4
        for (int k = 0; k < IN_F; ++k) {
            float av = ar[k];
            const float* wr = Wo1 + k * IN_F + j0;
#pragma unroll
            for (int jj = 0; jj < 3; ++jj) acc[jj] += av * wr[jj];
        }
        const float* gr = aggt + r * 44;
#pragma unroll 4
        for (int pp = 0; pp < 2 * PDIM; ++pp) {
            float av = gr[pp];
            const float* wr = Wo2 + pp * IN_F + j0;
#pragma unroll
            for (int jj = 0; jj < 3; ++jj) acc[jj] += av * wr[jj];
        }
#pragma unroll
        for (int jj = 0; jj < 3; ++jj)
            et[r * IN_F + j0 + jj] = acc[jj] + bo2[j0 + jj];
    }
    lgkm_barrier();   // et ready

    // h1 = elu(et@W1 + b1): 2 rows x 4 cols; W1 rows via wbuf halves + tail
    {
        float a0[4] = {0.f, 0.f, 0.f, 0.f};
        float a1[4] = {0.f, 0.f, 0.f, 0.f};
        const float* e0 = et + rA * IN_F;
        const float* e1 = et + rB * IN_F;
#pragma unroll
        for (int k = 0; k < IN_F; ++k) {
            const float* wr = (k < 32)
                ? wbuf + (k >> 4) * (16 * WPAD) + (k & 15) * WPAD
                : w1tail + (k - 32) * WPAD;
            const float4 w4 = *(const float4*)(wr + jc);
            float v0 = e0[k], v1 = e1[k];
            a0[0] += v0 * w4.x; a0[1] += v0 * w4.y;
            a0[2] += v0 * w4.z; a0[3] += v0 * w4.w;
            a1[0] += v1 * w4.x; a1[1] += v1 * w4.y;
            a1[2] += v1 * w4.z; a1[3] += v1 * w4.w;
        }
#pragma unroll
        for (int jj = 0; jj < 4; ++jj) {
            int j = jc + jj;
            float bj = b1[j < WIDTH ? j : WIDTH - 1];
            float v0 = a0[jj] + bj;
            float v1 = a1[jj] + bj;
            h1t[rA * WPAD + j] = (j < WIDTH) ? (v0 > 0.f ? v0 : expm1f(v0)) : 0.f;
            h1t[rB * WPAD + j] = (j < WIDTH) ? (v1 > 0.f ? v1 : expm1f(v1)) : 0.f;
        }
    }
    lgkm_barrier();   // h1t ready; W1 reads done -> wbuf reusable

    // ---- h2: 8 x 16-row W2 chunks, dbuf, loads 1 chunk ahead ----
    float a0[4] = {0.f, 0.f, 0.f, 0.f};
    float a1[4] = {0.f, 0.f, 0.f, 0.f};
    const float* h0 = h1t + rA * WPAD;
    const float* h1r = h1t + rB * WPAD;

#define COMPUTE_CHUNK(BUFI, K0)                                 \
    {                                                           \
        const float* wb = wbuf + (BUFI) * 2048;                 \
        _Pragma("unroll 4")                                     \
        for (int k = 0; k < 16; ++k) {                          \
            const float4 w4 = *(const float4*)(wb + k * WPAD + jc); \
            float v0 = h0[(K0) + k];                            \
            float v1 = h1r[(K0) + k];                           \
            a0[0] += v0 * w4.x; a0[1] += v0 * w4.y;             \
            a0[2] += v0 * w4.z; a0[3] += v0 * w4.w;             \
            a1[0] += v1 * w4.x; a1[1] += v1 * w4.y;             \
            a1[2] += v1 * w4.z; a1[3] += v1 * w4.w;             \
        }                                                       \
    }

    STORE_CHUNK(0, rvA); LOAD_CHUNK(rvB, 16);
    lgkm_barrier(); COMPUTE_CHUNK(0, 0);
    STORE_CHUNK(1, rvB); LOAD_CHUNK(rvA, 32);
    lgkm_barrier(); COMPUTE_CHUNK(1, 16);
    STORE_CHUNK(0, rvA); LOAD_CHUNK(rvB, 48);
    lgkm_barrier(); COMPUTE_CHUNK(0, 32);
    STORE_CHUNK(1, rvB); LOAD_CHUNK(rvA, 64);
    lgkm_barrier(); COMPUTE_CHUNK(1, 48);
    STORE_CHUNK(0, rvA); LOAD_CHUNK(rvB, 80);
    lgkm_barrier(); COMPUTE_CHUNK(0, 64);
    STORE_CHUNK(1, rvB); LOAD_CHUNK(rvA, 96);
    lgkm_barrier(); COMPUTE_CHUNK(1, 80);
    STORE_CHUNK(0, rvA); LOAD_CHUNK(rvB, 112);
    lgkm_barrier(); COMPUTE_CHUNK(0, 96);
    STORE_CHUNK(1, rvB);
    lgkm_barrier(); COMPUTE_CHUNK(1, 112);

    // h2 = elu(acc+b2) in-register; fold out = h2@W3; width-32 shfl reduce
    {
        float pc0[NCLS] = {0.f, 0.f, 0.f, 0.f, 0.f, 0.f};
        float pc1[NCLS] = {0.f, 0.f, 0.f, 0.f, 0.f, 0.f};
#pragma unroll
        for (int jj = 0; jj < 4; ++jj) {
            int j = jc + jj;
            float bj = b2[j < WIDTH ? j : WIDTH - 1];
            float v0 = a0[jj] + bj;
            float v1 = a1[jj] + bj;
            float g0 = (j < WIDTH) ? (v0 > 0.f ? v0 : expm1f(v0)) : 0.f;
            float g1 = (j < WIDTH) ? (v1 > 0.f ? v1 : expm1f(v1)) : 0.f;
            const float* w3r = w3buf + j * NCLS;   // pad rows are 0
#pragma unroll
            for (int cc = 0; cc < NCLS; ++cc) {
                pc0[cc] += g0 * w3r[cc];
                pc1[cc] += g1 * w3r[cc];
            }
        }
#pragma unroll
        for (int mm = 1; mm < 32; mm <<= 1) {
#pragma unroll
            for (int cc = 0; cc < NCLS; ++cc) {
                pc0[cc] += __shfl_xor(pc0[cc], mm, 32);
                pc1[cc] += __shfl_xor(pc1[cc], mm, 32);
            }
        }
        if (cg == 0) {
#pragma unroll
            for (int cc = 0; cc < NCLS; ++cc) {
                out[(size_t)(row0 + rA) * NCLS + cc] = pc0[cc] + b3[cc];
                out[(size_t)(row0 + rB) * NCLS + cc] = pc1[cc] + b3[cc];
            }
        }
    }
#undef STORE_CHUNK
#undef LOAD_CHUNK
#undef COMPUTE_CHUNK
}

extern "C" void kernel_launch(void* const* d_in, const int* in_sizes, int n_in,
                              void* d_out, int out_size, void* d_ws, size_t ws_size,
                              hipStream_t stream) {
    const float* x     = (const float*)d_in[0];
    const int*   batch = (const int*)d_in[1];
    // Only conv index NCONV-1 == 1 affects the output (loop discards earlier)
    const float* Ws  = (const float*)d_in[2] + IN_F * SDIM;
    const float* bs  = (const float*)d_in[3] + SDIM;
    const float* Wh  = (const float*)d_in[4] + IN_F * PDIM;
    const float* bh  = (const float*)d_in[5] + PDIM;
    const float* Wo1 = (const float*)d_in[6] + IN_F * IN_F;
    const float* Wo2 = (const float*)d_in[7] + 2 * PDIM * IN_F;
    const float* bo2 = (const float*)d_in[8] + IN_F;
    const float* W1  = (const float*)d_in[9];
    const float* b1  = (const float*)d_in[10];
    const float* W2  = (const float*)d_in[11];
    const float* b2  = (const float*)d_in[12];
    const float* W3  = (const float*)d_in[13];
    const float* b3  = (const float*)d_in[14];
    float* out = (float*)d_out;

    char* ws = (char*)d_ws;
    int*   ranges = (int*)(ws + OFF_RANGES);
    float* S      = (float*)(ws + OFF_S);
    float* H      = (float*)(ws + OFF_H);
    int*   KIDX   = (int*)(ws + OFF_KIDX);
    float* KW     = (float*)(ws + OFF_KW);

    k_sh<<<dim3(NPT * 32 / 256), dim3(256), 0, stream>>>(x, batch, Ws, bs, Wh, bh, S, H, ranges);
    k_knn<<<dim3(NPT / 8), dim3(256), 0, stream>>>((const float4*)S, batch, ranges, KIDX, KW);
    k_fused<<<dim3(NPT / ROWS), dim3(256), 0, stream>>>(x, H, KIDX, KW, Wo1, Wo2, bo2,
                                                        W1, b1, W2, b2, W3, b3, out);
}

// Round 22
// 77.796 us; speedup vs baseline: 1.1230x; 1.1230x over previous
//
#include <hip/hip_runtime.h>
#include <math.h>
#include <float.h>

// Problem constants (from reference)
#define NPT     16384
#define IN_F    34
#define SDIM    4
#define PDIM    22
#define KNN     8
#define WIDTH   126
#define WPAD    128    // padded width for conflict-free LDS
#define NCLS    6
#define ROWS    32     // rows per fused-MLP block (512 threads)

typedef unsigned long long u64;

// ---------------- workspace layout (bytes), total ~4.1 MB ----------------
#define OFF_RANGES 0
#define OFF_S      256
#define OFF_H      (OFF_S  + NPT*SDIM*4)
#define OFF_AGG    (OFF_H  + NPT*PDIM*4)     // NPT x 44: [mean(22) | max(22)]

// key bits = (float_bits(d2) << 32) | j : u64 order == lex (d2, idx) order ==
// jax.lax.top_k tie-breaking. d2 >= 0 -> the f64 view is positive, never
// NaN/Inf -> IEEE f64 order == unsigned bit order -> networks run on
// v_min_f64/v_max_f64 (CE = 2 instr vs 5 for u64).
#define INITK_BITS 0x7f7fffffffffffffULL

__device__ __forceinline__ void ce(double& a, double& b) {   // a=min, b=max
    double mn = __builtin_fmin(a, b);
    double mx = __builtin_fmax(a, b);
    a = mn; b = mx;
}
__device__ __forceinline__ double dmin64(double a, double b) {
    return __builtin_fmin(a, b);
}
__device__ __forceinline__ double pack_key(float d2, unsigned j) {
    return __longlong_as_double((long long)(((u64)__float_as_uint(d2) << 32) | j));
}

__device__ __forceinline__ void key_insert(double key, double* u) {
#pragma unroll
    for (int t = 0; t < KNN; ++t) {
        double mn = __builtin_fmin(key, u[t]);
        double mx = __builtin_fmax(key, u[t]);
        u[t] = mn;
        key  = mx;
    }
}

// lgkm-only barrier: waits LDS ops, leaves global prefetch loads in flight.
__device__ __forceinline__ void lgkm_barrier() {
    asm volatile("s_waitcnt lgkmcnt(0)" ::: "memory");
    __builtin_amdgcn_s_barrier();
    asm volatile("" ::: "memory");
}

// match reference numerics: rounded squares, sequential sum, no fma
__device__ __forceinline__ float dist2(const float4 a, const float4 b) {
    float d0 = a.x - b.x;
    float d1 = a.y - b.y;
    float d2 = a.z - b.z;
    float d3 = a.w - b.w;
    return __fadd_rn(__fadd_rn(__fadd_rn(__fmul_rn(d0, d0),
                                         __fmul_rn(d1, d1)),
                               __fmul_rn(d2, d2)),
                     __fmul_rn(d3, d3));
}

// 12-CE bitonic sort of a bitonic 8-sequence (m0..m7), ascending result
#define BITONIC8(m0,m1,m2,m3,m4,m5,m6,m7) \
    ce(m0,m4); ce(m1,m5); ce(m2,m6); ce(m3,m7); \
    ce(m0,m2); ce(m1,m3); ce(m4,m6); ce(m5,m7); \
    ce(m0,m1); ce(m2,m3); ce(m4,m5); ce(m6,m7);

// Batcher odd-even mergesort network for 8 keys (19 CE), ascending
#define SORT8(k0,k1,k2,k3,k4,k5,k6,k7) \
    ce(k0,k1); ce(k2,k3); ce(k4,k5); ce(k6,k7); \
    ce(k0,k2); ce(k1,k3); ce(k4,k6); ce(k5,k7); \
    ce(k1,k2); ce(k5,k6); \
    ce(k0,k4); ce(k1,k5); ce(k2,k6); ce(k3,k7); \
    ce(k2,k4); ce(k3,k5); \
    ce(k1,k2); ce(k3,k4); ce(k5,k6);

// ---------------------------------------------------------
// s = (x@Ws + bs) + 1000*batch ; h = x@Wh + bh  (conv index 1 weights).
__global__ __launch_bounds__(256) void k_sh(const float* __restrict__ x,
                                            const int* __restrict__ batch,
                                            const float* __restrict__ Ws,
                                            const float* __restrict__ bs,
                                            const float* __restrict__ Wh,
                                            const float* __restrict__ bh,
                                            float* __restrict__ S,
                                            float* __restrict__ H,
                                            int* __restrict__ ranges) {
    int t = blockIdx.x * blockDim.x + threadIdx.x;
    int i = t >> 5;
    int o = t & 31;
    if (i >= NPT) return;
    if (o == 31) {  // graph ranges from sorted batch
        int b = batch[i];
        if (i == 0 || batch[i - 1] != b) ranges[b * 2]     = i;
        if (i == NPT - 1 || batch[i + 1] != b) ranges[b * 2 + 1] = i + 1;
        return;
    }
    const float* xr = x + (size_t)i * IN_F;
    if (o < SDIM) {
        float acc = 0.f;
        for (int k = 0; k < IN_F; ++k) acc += xr[k] * Ws[k * SDIM + o];
        S[(size_t)i * SDIM + o] = (acc + bs[o]) + 1000.f * (float)batch[i];
    } else if (o < SDIM + PDIM) {
        int p = o - SDIM;
        float acc = 0.f;
        for (int k = 0; k < IN_F; ++k) acc += xr[k] * Wh[k * PDIM + p];
        H[(size_t)i * PDIM + p] = acc + bh[p];
    }
}

// Fused kNN + AGGREGATION (round-22): after the butterfly every lane holds
// the final sorted top-8 in registers, so the gather/aggregate is computed
// HERE (lane t<22 handles H-dim t; 8 independent L2-hot loads per lane,
// hidden by co-resident scanning waves) and AGG[q][44] is written directly.
// This deletes k_fused's worst phase (KIDX->KW->H dependent chain right
// after launch) and the KIDX/KW round-trip. Numerics bit-identical: same
// sorted e=0..7 iteration order, same exp, same sequential sum.
__global__ __launch_bounds__(256, 4) void k_knn(const float4* __restrict__ S4,
                                                const int* __restrict__ batch,
                                                const int* __restrict__ ranges,
                                                const float* __restrict__ H,
                                                float* __restrict__ AGG) {
    const int tid = threadIdx.x;
    const int q   = blockIdx.x * 8 + (tid >> 5);
    const int t   = tid & 31;
    const int b   = batch[q];
    const int gs  = ranges[b * 2];
    const int len = ranges[b * 2 + 1] - gs;
    const float4 sq = S4[q];

    double u[KNN];
    const double initk = __longlong_as_double((long long)INITK_BITS);
#pragma unroll
    for (int e = 0; e < KNN; ++e) u[e] = initk;

    int j = gs + t;
    int done = 0;

    const int nfull8 = len >> 8;
    for (int bb = 0; bb < nfull8; ++bb, j += 256) {
        const float4* p = S4 + j;
        float4 s0 = p[0];
        float4 s1 = p[32];
        float4 s2 = p[64];
        float4 s3 = p[96];
        float4 s4 = p[128];
        float4 s5 = p[160];
        float4 s6 = p[192];
        float4 s7 = p[224];
        double k0 = pack_key(dist2(sq, s0), (unsigned)(j));
        double k1 = pack_key(dist2(sq, s1), (unsigned)(j + 32));
        double k2 = pack_key(dist2(sq, s2), (unsigned)(j + 64));
        double k3 = pack_key(dist2(sq, s3), (unsigned)(j + 96));
        double k4 = pack_key(dist2(sq, s4), (unsigned)(j + 128));
        double k5 = pack_key(dist2(sq, s5), (unsigned)(j + 160));
        double k6 = pack_key(dist2(sq, s6), (unsigned)(j + 192));
        double k7 = pack_key(dist2(sq, s7), (unsigned)(j + 224));
        SORT8(k0, k1, k2, k3, k4, k5, k6, k7);
        double m0 = dmin64(k0, u[7]);
        double m1 = dmin64(k1, u[6]);
        double m2 = dmin64(k2, u[5]);
        double m3 = dmin64(k3, u[4]);
        double m4 = dmin64(k4, u[3]);
        double m5 = dmin64(k5, u[2]);
        double m6 = dmin64(k6, u[1]);
        double m7 = dmin64(k7, u[0]);
        BITONIC8(m0, m1, m2, m3, m4, m5, m6, m7);
        u[0] = m0; u[1] = m1; u[2] = m2; u[3] = m3;
        u[4] = m4; u[5] = m5; u[6] = m6; u[7] = m7;
    }
    done = nfull8 << 8;

    if (len - done >= 128) {
        const float4* p = S4 + j;
        float4 s0 = p[0];
        float4 s1 = p[32];
        float4 s2 = p[64];
        float4 s3 = p[96];
        double k0 = pack_key(dist2(sq, s0), (unsigned)(j));
        double k1 = pack_key(dist2(sq, s1), (unsigned)(j + 32));
        double k2 = pack_key(dist2(sq, s2), (unsigned)(j + 64));
        double k3 = pack_key(dist2(sq, s3), (unsigned)(j + 96));
        ce(k0, k1); ce(k2, k3); ce(k0, k2); ce(k1, k3); ce(k1, k2);
        double m0 = dmin64(k0, u[7]);
        double m1 = dmin64(k1, u[6]);
        double m2 = dmin64(k2, u[5]);
        double m3 = dmin64(k3, u[4]);
        double m4 = u[3], m5 = u[2], m6 = u[1], m7 = u[0];
        BITONIC8(m0, m1, m2, m3, m4, m5, m6, m7);
        u[0] = m0; u[1] = m1; u[2] = m2; u[3] = m3;
        u[4] = m4; u[5] = m5; u[6] = m6; u[7] = m7;
        done += 128;
    }

    for (int m = done + t; m < len; m += 32) {
        int jj = gs + m;
        key_insert(pack_key(dist2(sq, S4[jj]), (unsigned)jj), u);
    }

#pragma unroll
    for (int mm = 1; mm < 32; mm <<= 1) {
        double p0 = __shfl_xor(u[0], mm, 32);
        double p1 = __shfl_xor(u[1], mm, 32);
        double p2 = __shfl_xor(u[2], mm, 32);
        double p3 = __shfl_xor(u[3], mm, 32);
        double p4 = __shfl_xor(u[4], mm, 32);
        double p5 = __shfl_xor(u[5], mm, 32);
        double p6 = __shfl_xor(u[6], mm, 32);
        double p7 = __shfl_xor(u[7], mm, 32);
        double m0 = dmin64(u[0], p7);
        double m1 = dmin64(u[1], p6);
        double m2 = dmin64(u[2], p5);
        double m3 = dmin64(u[3], p4);
        double m4 = dmin64(u[4], p3);
        double m5 = dmin64(u[5], p2);
        double m6 = dmin64(u[6], p1);
        double m7 = dmin64(u[7], p0);
        BITONIC8(m0, m1, m2, m3, m4, m5, m6, m7);
        u[0] = m0; u[1] = m1; u[2] = m2; u[3] = m3;
        u[4] = m4; u[5] = m5; u[6] = m6; u[7] = m7;
    }

    // aggregation in-kernel: all lanes unpack (idx, w); lane t<22 reduces dim t
    {
        int   idx[KNN];
        float w[KNN];
#pragma unroll
        for (int e = 0; e < KNN; ++e) {
            u64 bits = (u64)__double_as_longlong(u[e]);
            idx[e] = (int)(unsigned)(bits & 0xffffffffu);
            w[e]   = expf(-10.f * __uint_as_float((unsigned)(bits >> 32)));
        }
        if (t < PDIM) {
            float s = 0.f, mx = -FLT_MAX;
#pragma unroll
            for (int e = 0; e < KNN; ++e) {
                float v = H[(size_t)idx[e] * PDIM + t] * w[e];
                s += v; mx = fmaxf(mx, v);
            }
            AGG[(size_t)q * 44 + t]        = s * 0.125f;
            AGG[(size_t)q * 44 + PDIM + t] = mx;
        }
    }
}

// Fused MLP (round-19 structure minus the gather phase): first phase is now
// pure coalesced staging (x, W1, W3, AGG); everything downstream identical.
// XCD swizzle keeps each graph's blocks on one XCD (round-19 proven).
__global__ __launch_bounds__(512, 4) void k_fused(
        const float* __restrict__ x,
        const float* __restrict__ AGG,
        const float* __restrict__ Wo1,
        const float* __restrict__ Wo2,
        const float* __restrict__ bo2,
        const float* __restrict__ W1,
        const float* __restrict__ b1,
        const float* __restrict__ W2,
        const float* __restrict__ b2,
        const float* __restrict__ W3,
        const float* __restrict__ b3,
        float* __restrict__ out) {
    __shared__ float xt[ROWS * IN_F];       // 32x34
    __shared__ float aggt[ROWS * 2 * PDIM]; // 32x44
    __shared__ float et[ROWS * IN_F];       // 32x34
    __shared__ float h1t[ROWS * WPAD];      // 32x128 (cols 126/127 = 0)
    __shared__ float wbuf[2 * 32 * WPAD];   // 2 x 32x128: W1 split, then W2 dbuf
    __shared__ float w3buf[WPAD * NCLS];    // 128x6, rows 126/127 = 0
                                            // total = 66560 B -> 2 blocks/CU

    const int tid  = threadIdx.x;
    const int r    = tid >> 4;              // et mapping: row 0..31
    const int c    = tid & 15;              //             lane 0..15
    const int p    = tid >> 5;              // h1/h2/out: row-pair 0..15
    const int cg   = tid & 31;              //            col-group 0..31
    // XCD swizzle: dispatch d -> XCD d%8; logical block (d&7)*64+(d>>3)
    const int lb   = ((blockIdx.x & 7) << 6) | (blockIdx.x >> 3);
    const int row0 = lb * ROWS;
    const int rA   = 2 * p;
    const int rB   = 2 * p + 1;
    const int jc   = 4 * cg;                // this thread's 4 cols (0..124)

    // ---- staging: x, AGG, W1 (split over wbuf halves), W3 -- all coalesced
    for (int t = tid; t < ROWS * IN_F; t += 512)
        xt[t] = x[(size_t)row0 * IN_F + t];
    for (int t = tid; t < ROWS * 2 * PDIM; t += 512)
        aggt[t] = AGG[(size_t)row0 * 44 + t];
    for (int t = tid; t < IN_F * WPAD; t += 512) {
        int k = t >> 7, j = t & 127;
        wbuf[(k >> 5) * (32 * WPAD) + (k & 31) * WPAD + j] =
            (j < WIDTH) ? W1[k * WIDTH + j] : 0.f;
    }
    for (int t = tid; t < WPAD * NCLS; t += 512) {
        int k = t / NCLS;
        w3buf[t] = (k < WIDTH) ? W3[t] : 0.f;
    }
    lgkm_barrier();   // xt, aggt, W1, w3 visible

    // issue W2 chunk0 loads NOW; they drain under et + h1 compute.
    float rvA[8], rvB[8];
#pragma unroll
    for (int i = 0; i < 8; ++i) {
        int e = i * 512 + tid, kk = e >> 7, j = e & 127;
        rvA[i] = (j < WIDTH) ? W2[(size_t)kk * WIDTH + j] : 0.f;  // rows 0..31
    }

    // et = x@Wo1 + agg@Wo2 + bo2 ; 3-wide chunks, j0=min(3c,31)
    {
        const int j0 = (3 * c < 31) ? 3 * c : 31;
        float acc[3] = {0.f, 0.f, 0.f};
        const float* ar = xt + r * IN_F;
#pragma unroll 4
        for (int k = 0; k < IN_F; ++k) {
            float av = ar[k];
            const float* wr = Wo1 + k * IN_F + j0;
#pragma unroll
            for (int jj = 0; jj < 3; ++jj) acc[jj] += av * wr[jj];
        }
        const float* gr = aggt + r * 44;
#pragma unroll 4
        for (int pp = 0; pp < 2 * PDIM; ++pp) {
            float av = gr[pp];
            const float* wr = Wo2 + pp * IN_F + j0;
#pragma unroll
            for (int jj = 0; jj < 3; ++jj) acc[jj] += av * wr[jj];
        }
#pragma unroll
        for (int jj = 0; jj < 3; ++jj)
            et[r * IN_F + j0 + jj] = acc[jj] + bo2[j0 + jj];
    }
    lgkm_barrier();   // et ready

    // h1 = elu(et@W1 + b1): 2 rows x 4 cols, weight float4 shared
    {
        float a0[4] = {0.f, 0.f, 0.f, 0.f};
        float a1[4] = {0.f, 0.f, 0.f, 0.f};
        const float* e0 = et + rA * IN_F;
        const float* e1 = et + rB * IN_F;
#pragma unroll 4
        for (int k = 0; k < IN_F; ++k) {
            const float* wr = wbuf + (k >> 5) * (32 * WPAD) + (k & 31) * WPAD;
            const float4 w4 = *(const float4*)(wr + jc);
            float v0 = e0[k], v1 = e1[k];
            a0[0] += v0 * w4.x; a0[1] += v0 * w4.y;
            a0[2] += v0 * w4.z; a0[3] += v0 * w4.w;
            a1[0] += v1 * w4.x; a1[1] += v1 * w4.y;
            a1[2] += v1 * w4.z; a1[3] += v1 * w4.w;
        }
#pragma unroll
        for (int jj = 0; jj < 4; ++jj) {
            int j = jc + jj;
            float bj = b1[j < WIDTH ? j : WIDTH - 1];
            float v0 = a0[jj] + bj;
            float v1 = a1[jj] + bj;
            h1t[rA * WPAD + j] = (j < WIDTH) ? (v0 > 0.f ? v0 : expm1f(v0)) : 0.f;
            h1t[rB * WPAD + j] = (j < WIDTH) ? (v1 > 0.f ? v1 : expm1f(v1)) : 0.f;
        }
    }
    lgkm_barrier();   // h1t ready; ALL W1 reads done -> wbuf reusable

    // ---- h2 with double-buffered W2; 2 rows x 4 cols per thread ----
    float a0[4] = {0.f, 0.f, 0.f, 0.f};
    float a1[4] = {0.f, 0.f, 0.f, 0.f};
    const float* h0 = h1t + rA * WPAD;
    const float* h1r = h1t + rB * WPAD;

#define STORE_CHUNK(BUFI, RV)                                   \
    _Pragma("unroll")                                           \
    for (int i = 0; i < 8; ++i)                                 \
        wbuf[(BUFI) * 4096 + i * 512 + tid] = RV[i];

#define LOAD_CHUNK(RV, K0)                                      \
    _Pragma("unroll")                                           \
    for (int i = 0; i < 8; ++i) {                               \
        int e = i * 512 + tid, kk = e >> 7, j = e & 127;        \
        int row = (K0) + kk;                                    \
        RV[i] = (j < WIDTH && row < WIDTH)                      \
                    ? W2[(size_t)row * WIDTH + j] : 0.f;        \
    }

#define COMPUTE_CHUNK(BUFI, K0)                                 \
    {                                                           \
        const float* wb = wbuf + (BUFI) * 4096;                 \
        _Pragma("unroll 4")                                     \
        for (int k = 0; k < 32; ++k) {                          \
            const float4 w4 = *(const float4*)(wb + k * WPAD + jc); \
            float v0 = h0[(K0) + k];                            \
            float v1 = h1r[(K0) + k];                           \
            a0[0] += v0 * w4.x; a0[1] += v0 * w4.y;             \
            a0[2] += v0 * w4.z; a0[3] += v0 * w4.w;             \
            a1[0] += v1 * w4.x; a1[1] += v1 * w4.y;             \
            a1[2] += v1 * w4.z; a1[3] += v1 * w4.w;             \
        }                                                       \
    }

    STORE_CHUNK(0, rvA);  LOAD_CHUNK(rvB, 32);
    lgkm_barrier();
    COMPUTE_CHUNK(0, 0);
    STORE_CHUNK(1, rvB);  LOAD_CHUNK(rvA, 64);
    lgkm_barrier();
    COMPUTE_CHUNK(1, 32);
    STORE_CHUNK(0, rvA);  LOAD_CHUNK(rvB, 96);
    lgkm_barrier();
    COMPUTE_CHUNK(0, 64);
    STORE_CHUNK(1, rvB);
    lgkm_barrier();
    COMPUTE_CHUNK(1, 96);

    // h2 = elu(acc+b2) in-register; fold out = h2@W3; width-32 shfl reduce
    {
        float pc0[NCLS] = {0.f, 0.f, 0.f, 0.f, 0.f, 0.f};
        float pc1[NCLS] = {0.f, 0.f, 0.f, 0.f, 0.f, 0.f};
#pragma unroll
        for (int jj = 0; jj < 4; ++jj) {
            int j = jc + jj;
            float bj = b2[j < WIDTH ? j : WIDTH - 1];
            float v0 = a0[jj] + bj;
            float v1 = a1[jj] + bj;
            float g0 = (j < WIDTH) ? (v0 > 0.f ? v0 : expm1f(v0)) : 0.f;
            float g1 = (j < WIDTH) ? (v1 > 0.f ? v1 : expm1f(v1)) : 0.f;
            const float* w3r = w3buf + j * NCLS;   // pad rows are 0
#pragma unroll
            for (int cc = 0; cc < NCLS; ++cc) {
                pc0[cc] += g0 * w3r[cc];
                pc1[cc] += g1 * w3r[cc];
            }
        }
#pragma unroll
        for (int mm = 1; mm < 32; mm <<= 1) {
#pragma unroll
            for (int cc = 0; cc < NCLS; ++cc) {
                pc0[cc] += __shfl_xor(pc0[cc], mm, 32);
                pc1[cc] += __shfl_xor(pc1[cc], mm, 32);
            }
        }
        if (cg == 0) {
#pragma unroll
            for (int cc = 0; cc < NCLS; ++cc) {
                out[(size_t)(row0 + rA) * NCLS + cc] = pc0[cc] + b3[cc];
                out[(size_t)(row0 + rB) * NCLS + cc] = pc1[cc] + b3[cc];
            }
        }
    }
#undef STORE_CHUNK
#undef LOAD_CHUNK
#undef COMPUTE_CHUNK
}

extern "C" void kernel_launch(void* const* d_in, const int* in_sizes, int n_in,
                              void* d_out, int out_size, void* d_ws, size_t ws_size,
                              hipStream_t stream) {
    const float* x     = (const float*)d_in[0];
    const int*   batch = (const int*)d_in[1];
    // Only conv index NCONV-1 == 1 affects the output (loop discards earlier)
    const float* Ws  = (const float*)d_in[2] + IN_F * SDIM;
    const float* bs  = (const float*)d_in[3] + SDIM;
    const float* Wh  = (const float*)d_in[4] + IN_F * PDIM;
    const float* bh  = (const float*)d_in[5] + PDIM;
    const float* Wo1 = (const float*)d_in[6] + IN_F * IN_F;
    const float* Wo2 = (const float*)d_in[7] + 2 * PDIM * IN_F;
    const float* bo2 = (const float*)d_in[8] + IN_F;
    const float* W1  = (const float*)d_in[9];
    const float* b1  = (const float*)d_in[10];
    const float* W2  = (const float*)d_in[11];
    const float* b2  = (const float*)d_in[12];
    const float* W3  = (const float*)d_in[13];
    const float* b3  = (const float*)d_in[14];
    float* out = (float*)d_out;

    char* ws = (char*)d_ws;
    int*   ranges = (int*)(ws + OFF_RANGES);
    float* S      = (float*)(ws + OFF_S);
    float* H      = (float*)(ws + OFF_H);
    float* AGG    = (float*)(ws + OFF_AGG);

    k_sh<<<dim3(NPT * 32 / 256), dim3(256), 0, stream>>>(x, batch, Ws, bs, Wh, bh, S, H, ranges);
    k_knn<<<dim3(NPT / 8), dim3(256), 0, stream>>>((const float4*)S, batch, ranges, H, AGG);
    k_fused<<<dim3(NPT / ROWS), dim3(512), 0, stream>>>(x, AGG, Wo1, Wo2, bo2,
                                                        W1, b1, W2, b2, W3, b3, out);
}

// Round 23
// 71.906 us; speedup vs baseline: 1.2150x; 1.0819x over previous
//
#include <hip/hip_runtime.h>
#include <math.h>
#include <float.h>

// Problem constants (from reference)
#define NPT     16384
#define IN_F    34
#define SDIM    4
#define PDIM    22
#define KNN     8
#define WIDTH   126
#define WPAD    128    // padded width for conflict-free LDS
#define NCLS    6
#define ROWS    32     // rows per fused-MLP block (512 threads)

typedef unsigned long long u64;

// ---------------- workspace layout (bytes), total ~3 MB ----------------
#define OFF_RANGES 0
#define OFF_S      256
#define OFF_H      (OFF_S  + NPT*SDIM*4)
#define OFF_KIDX   (OFF_H  + NPT*PDIM*4)
#define OFF_KW     (OFF_KIDX + NPT*KNN*4)

// key bits = (float_bits(d2) << 32) | j : u64 order == lex (d2, idx) order ==
// jax.lax.top_k tie-breaking. d2 >= 0 -> the f64 view is positive, never
// NaN/Inf -> IEEE f64 order == unsigned bit order -> networks run on
// v_min_f64/v_max_f64 (CE = 2 instr vs 5 for u64).
#define INITK_BITS 0x7f7fffffffffffffULL

__device__ __forceinline__ void ce(double& a, double& b) {   // a=min, b=max
    double mn = __builtin_fmin(a, b);
    double mx = __builtin_fmax(a, b);
    a = mn; b = mx;
}
__device__ __forceinline__ double dmin64(double a, double b) {
    return __builtin_fmin(a, b);
}
__device__ __forceinline__ double pack_key(float d2, unsigned j) {
    return __longlong_as_double((long long)(((u64)__float_as_uint(d2) << 32) | j));
}

__device__ __forceinline__ void key_insert(double key, double* u) {
#pragma unroll
    for (int t = 0; t < KNN; ++t) {
        double mn = __builtin_fmin(key, u[t]);
        double mx = __builtin_fmax(key, u[t]);
        u[t] = mn;
        key  = mx;
    }
}

// lgkm-only barrier (keeps W2 prefetch loads in flight across barriers)
__device__ __forceinline__ void lgkm_barrier() {
    asm volatile("s_waitcnt lgkmcnt(0)" ::: "memory");
    __builtin_amdgcn_s_barrier();
    asm volatile("" ::: "memory");
}

// match reference numerics: rounded squares, sequential sum, no fma
__device__ __forceinline__ float dist2(const float4 a, const float4 b) {
    float d0 = a.x - b.x;
    float d1 = a.y - b.y;
    float d2 = a.z - b.z;
    float d3 = a.w - b.w;
    return __fadd_rn(__fadd_rn(__fadd_rn(__fmul_rn(d0, d0),
                                         __fmul_rn(d1, d1)),
                               __fmul_rn(d2, d2)),
                     __fmul_rn(d3, d3));
}

// 12-CE bitonic sort of a bitonic 8-sequence (m0..m7), ascending result
#define BITONIC8(m0,m1,m2,m3,m4,m5,m6,m7) \
    ce(m0,m4); ce(m1,m5); ce(m2,m6); ce(m3,m7); \
    ce(m0,m2); ce(m1,m3); ce(m4,m6); ce(m5,m7); \
    ce(m0,m1); ce(m2,m3); ce(m4,m5); ce(m6,m7);

// Batcher odd-even mergesort network for 8 keys (19 CE), ascending
#define SORT8(k0,k1,k2,k3,k4,k5,k6,k7) \
    ce(k0,k1); ce(k2,k3); ce(k4,k5); ce(k6,k7); \
    ce(k0,k2); ce(k1,k3); ce(k4,k6); ce(k5,k7); \
    ce(k1,k2); ce(k5,k6); \
    ce(k0,k4); ce(k1,k5); ce(k2,k6); ce(k3,k7); \
    ce(k2,k4); ce(k3,k5); \
    ce(k1,k2); ce(k3,k4); ce(k5,k6);

// ---------------------------------------------------------
// s = (x@Ws + bs) + 1000*batch ; h = x@Wh + bh  (conv index 1 weights).
__global__ __launch_bounds__(256) void k_sh(const float* __restrict__ x,
                                            const int* __restrict__ batch,
                                            const float* __restrict__ Ws,
                                            const float* __restrict__ bs,
                                            const float* __restrict__ Wh,
                                            const float* __restrict__ bh,
                                            float* __restrict__ S,
                                            float* __restrict__ H,
                                            int* __restrict__ ranges) {
    int t = blockIdx.x * blockDim.x + threadIdx.x;
    int i = t >> 5;
    int o = t & 31;
    if (i >= NPT) return;
    if (o == 31) {  // graph ranges from sorted batch
        int b = batch[i];
        if (i == 0 || batch[i - 1] != b) ranges[b * 2]     = i;
        if (i == NPT - 1 || batch[i + 1] != b) ranges[b * 2 + 1] = i + 1;
        return;
    }
    const float* xr = x + (size_t)i * IN_F;
    if (o < SDIM) {
        float acc = 0.f;
        for (int k = 0; k < IN_F; ++k) acc += xr[k] * Ws[k * SDIM + o];
        S[(size_t)i * SDIM + o] = (acc + bs[o]) + 1000.f * (float)batch[i];
    } else if (o < SDIM + PDIM) {
        int p = o - SDIM;
        float acc = 0.f;
        for (int k = 0; k < IN_F; ++k) acc += xr[k] * Wh[k * PDIM + p];
        H[(size_t)i * PDIM + p] = acc + bh[p];
    }
}

// Fused kNN, round-23: 16 lanes per query (was 32). Scan-network cost is
// lane-count-invariant ((len/8)x66 instr), but the butterfly merge costs
// lanes*log2(lanes)*46: 32 lanes = 7.4K instr/query, 16 lanes = 2.9K
// (-18% total k_knn instructions). Residency unchanged: launch_bounds(256,4)
// caps at 16 waves/CU either way. Same exact u64-as-f64 key order.
__global__ __launch_bounds__(256, 4) void k_knn(const float4* __restrict__ S4,
                                                const int* __restrict__ batch,
                                                const int* __restrict__ ranges,
                                                int* __restrict__ KIDX,
                                                float* __restrict__ KW) {
    const int tid = threadIdx.x;
    const int q   = blockIdx.x * 16 + (tid >> 4);
    const int t   = tid & 15;
    const int b   = batch[q];
    const int gs  = ranges[b * 2];
    const int len = ranges[b * 2 + 1] - gs;
    const float4 sq = S4[q];

    double u[KNN];
    const double initk = __longlong_as_double((long long)INITK_BITS);
#pragma unroll
    for (int e = 0; e < KNN; ++e) u[e] = initk;

    int j = gs + t;
    int done = 0;

    // full 128-candidate (8/lane, 16 lanes) batches
    const int nfull8 = len >> 7;
    for (int bb = 0; bb < nfull8; ++bb, j += 128) {
        const float4* p = S4 + j;
        float4 s0 = p[0];
        float4 s1 = p[16];
        float4 s2 = p[32];
        float4 s3 = p[48];
        float4 s4 = p[64];
        float4 s5 = p[80];
        float4 s6 = p[96];
        float4 s7 = p[112];
        double k0 = pack_key(dist2(sq, s0), (unsigned)(j));
        double k1 = pack_key(dist2(sq, s1), (unsigned)(j + 16));
        double k2 = pack_key(dist2(sq, s2), (unsigned)(j + 32));
        double k3 = pack_key(dist2(sq, s3), (unsigned)(j + 48));
        double k4 = pack_key(dist2(sq, s4), (unsigned)(j + 64));
        double k5 = pack_key(dist2(sq, s5), (unsigned)(j + 80));
        double k6 = pack_key(dist2(sq, s6), (unsigned)(j + 96));
        double k7 = pack_key(dist2(sq, s7), (unsigned)(j + 112));
        SORT8(k0, k1, k2, k3, k4, k5, k6, k7);
        double m0 = dmin64(k0, u[7]);
        double m1 = dmin64(k1, u[6]);
        double m2 = dmin64(k2, u[5]);
        double m3 = dmin64(k3, u[4]);
        double m4 = dmin64(k4, u[3]);
        double m5 = dmin64(k5, u[2]);
        double m6 = dmin64(k6, u[1]);
        double m7 = dmin64(k7, u[0]);
        BITONIC8(m0, m1, m2, m3, m4, m5, m6, m7);
        u[0] = m0; u[1] = m1; u[2] = m2; u[3] = m3;
        u[4] = m4; u[5] = m5; u[6] = m6; u[7] = m7;
    }
    done = nfull8 << 7;

    // at most one 64-candidate (4/lane) batch
    if (len - done >= 64) {
        const float4* p = S4 + j;
        float4 s0 = p[0];
        float4 s1 = p[16];
        float4 s2 = p[32];
        float4 s3 = p[48];
        double k0 = pack_key(dist2(sq, s0), (unsigned)(j));
        double k1 = pack_key(dist2(sq, s1), (unsigned)(j + 16));
        double k2 = pack_key(dist2(sq, s2), (unsigned)(j + 32));
        double k3 = pack_key(dist2(sq, s3), (unsigned)(j + 48));
        ce(k0, k1); ce(k2, k3); ce(k0, k2); ce(k1, k3); ce(k1, k2);
        double m0 = dmin64(k0, u[7]);
        double m1 = dmin64(k1, u[6]);
        double m2 = dmin64(k2, u[5]);
        double m3 = dmin64(k3, u[4]);
        double m4 = u[3], m5 = u[2], m6 = u[1], m7 = u[0];
        BITONIC8(m0, m1, m2, m3, m4, m5, m6, m7);
        u[0] = m0; u[1] = m1; u[2] = m2; u[3] = m3;
        u[4] = m4; u[5] = m5; u[6] = m6; u[7] = m7;
        done += 64;
        j += 64;
    }

    // tail: per-lane <=4 singleton inserts (exact; order irrelevant)
    for (int m = done + t; m < len; m += 16) {
        int jj = gs + m;
        key_insert(pack_key(dist2(sq, S4[jj]), (unsigned)jj), u);
    }

    // butterfly across the 16-lane group: merge two sorted-8 lists per step
#pragma unroll
    for (int mm = 1; mm < 16; mm <<= 1) {
        double p0 = __shfl_xor(u[0], mm, 16);
        double p1 = __shfl_xor(u[1], mm, 16);
        double p2 = __shfl_xor(u[2], mm, 16);
        double p3 = __shfl_xor(u[3], mm, 16);
        double p4 = __shfl_xor(u[4], mm, 16);
        double p5 = __shfl_xor(u[5], mm, 16);
        double p6 = __shfl_xor(u[6], mm, 16);
        double p7 = __shfl_xor(u[7], mm, 16);
        double m0 = dmin64(u[0], p7);
        double m1 = dmin64(u[1], p6);
        double m2 = dmin64(u[2], p5);
        double m3 = dmin64(u[3], p4);
        double m4 = dmin64(u[4], p3);
        double m5 = dmin64(u[5], p2);
        double m6 = dmin64(u[6], p1);
        double m7 = dmin64(u[7], p0);
        BITONIC8(m0, m1, m2, m3, m4, m5, m6, m7);
        u[0] = m0; u[1] = m1; u[2] = m2; u[3] = m3;
        u[4] = m4; u[5] = m5; u[6] = m6; u[7] = m7;
    }

    if (t == 0) {
#pragma unroll
        for (int e = 0; e < KNN; ++e) {
            u64 bits = (u64)__double_as_longlong(u[e]);
            float d = __uint_as_float((unsigned)(bits >> 32));
            KIDX[(size_t)q * KNN + e] = (int)(unsigned)(bits & 0xffffffffu);
            KW[(size_t)q * KNN + e]   = expf(-10.f * d);
        }
    }
}

// Fused gather+MLP (round-19 version, verbatim -- 74.1us baseline):
// reg-blocked 2 rows x 4 cols, W2 reg-staged double-buffer, lgkm barriers,
// XCD swizzle lb=(bid&7)*64+(bid>>3) (each graph's blocks on one XCD).
__global__ __launch_bounds__(512, 4) void k_fused(
        const float* __restrict__ x,
        const float* __restrict__ H,
        const int* __restrict__ KIDX,
        const float* __restrict__ KW,
        const float* __restrict__ Wo1,
        const float* __restrict__ Wo2,
        const float* __restrict__ bo2,
        const float* __restrict__ W1,
        const float* __restrict__ b1,
        const float* __restrict__ W2,
        const float* __restrict__ b2,
        const float* __restrict__ W3,
        const float* __restrict__ b3,
        float* __restrict__ out) {
    __shared__ float xt[ROWS * IN_F];       // 32x34
    __shared__ float aggt[ROWS * 2 * PDIM]; // 32x44
    __shared__ float et[ROWS * IN_F];       // 32x34
    __shared__ float h1t[ROWS * WPAD];      // 32x128 (cols 126/127 = 0)
    __shared__ float wbuf[2 * 32 * WPAD];   // 2 x 32x128: W1 split, then W2 dbuf
    __shared__ float w3buf[WPAD * NCLS];    // 128x6, rows 126/127 = 0
                                            // total = 66560 B -> 2 blocks/CU

    const int tid  = threadIdx.x;
    const int r    = tid >> 4;              // gather/et mapping: row 0..31
    const int c    = tid & 15;              //                    lane 0..15
    const int p    = tid >> 5;              // h1/h2/out: row-pair 0..15
    const int cg   = tid & 31;              //            col-group 0..31
    const int lb   = ((blockIdx.x & 7) << 6) | (blockIdx.x >> 3);
    const int row0 = lb * ROWS;
    const int gi   = row0 + r;
    const int rA   = 2 * p;
    const int rB   = 2 * p + 1;
    const int jc   = 4 * cg;                // this thread's 4 cols (0..124)

    // ---- staging: x, W1 (rows split over both wbuf halves), W3 ----
    for (int t = tid; t < ROWS * IN_F; t += 512)
        xt[t] = x[(size_t)row0 * IN_F + t];
    for (int t = tid; t < IN_F * WPAD; t += 512) {
        int k = t >> 7, j = t & 127;
        wbuf[(k >> 5) * (32 * WPAD) + (k & 31) * WPAD + j] =
            (j < WIDTH) ? W1[k * WIDTH + j] : 0.f;
    }
    for (int t = tid; t < WPAD * NCLS; t += 512) {
        int k = t / NCLS;
        w3buf[t] = (k < WIDTH) ? W3[t] : 0.f;
    }

    // gather + aggregate: lane c<11 handles dims {c, c+11}
    if (c < 11) {
        const int p0 = c, p1 = c + 11;
        float s0 = 0.f, s1 = 0.f;
        float m0 = -FLT_MAX, m1 = -FLT_MAX;
#pragma unroll
        for (int k = 0; k < KNN; ++k) {
            int   j = KIDX[(size_t)gi * KNN + k];
            float w = KW[(size_t)gi * KNN + k];
            const float* hr = H + (size_t)j * PDIM;
            float v0 = hr[p0] * w; s0 += v0; m0 = fmaxf(m0, v0);
            float v1 = hr[p1] * w; s1 += v1; m1 = fmaxf(m1, v1);
        }
        aggt[r * 44 + p0] = s0 * 0.125f; aggt[r * 44 + PDIM + p0] = m0;
        aggt[r * 44 + p1] = s1 * 0.125f; aggt[r * 44 + PDIM + p1] = m1;
    }
    lgkm_barrier();   // xt, W1, w3, aggt visible

    // issue W2 chunk0 loads NOW; they drain under et + h1 compute.
    float rvA[8], rvB[8];
#pragma unroll
    for (int i = 0; i < 8; ++i) {
        int e = i * 512 + tid, kk = e >> 7, j = e & 127;
        rvA[i] = (j < WIDTH) ? W2[(size_t)kk * WIDTH + j] : 0.f;  // rows 0..31
    }

    // et = x@Wo1 + agg@Wo2 + bo2 ; 3-wide chunks, j0=min(3c,31)
    {
        const int j0 = (3 * c < 31) ? 3 * c : 31;
        float acc[3] = {0.f, 0.f, 0.f};
        const float* ar = xt + r * IN_F;
#pragma unroll 4
        for (int k = 0; k < IN_F; ++k) {
            float av = ar[k];
            const float* wr = Wo1 + k * IN_F + j0;
#pragma unroll
            for (int jj = 0; jj < 3; ++jj) acc[jj] += av * wr[jj];
        }
        const float* gr = aggt + r * 44;
#pragma unroll 4
        for (int pp = 0; pp < 2 * PDIM; ++pp) {
            float av = gr[pp];
            const float* wr = Wo2 + pp * IN_F + j0;
#pragma unroll
            for (int jj = 0; jj < 3; ++jj) acc[jj] += av * wr[jj];
        }
#pragma unroll
        for (int jj = 0; jj < 3; ++jj)
            et[r * IN_F + j0 + jj] = acc[jj] + bo2[j0 + jj];
    }
    lgkm_barrier();   // et ready

    // h1 = elu(et@W1 + b1): thread = (p,cg), 2 rows x 4 cols
    {
        float a0[4] = {0.f, 0.f, 0.f, 0.f};
        float a1[4] = {0.f, 0.f, 0.f, 0.f};
        const float* e0 = et + rA * IN_F;
        const float* e1 = et + rB * IN_F;
#pragma unroll 4
        for (int k = 0; k < IN_F; ++k) {
            const float* wr = wbuf + (k >> 5) * (32 * WPAD) + (k & 31) * WPAD;
            const float4 w4 = *(const float4*)(wr + jc);
            float v0 = e0[k], v1 = e1[k];
            a0[0] += v0 * w4.x; a0[1] += v0 * w4.y;
            a0[2] += v0 * w4.z; a0[3] += v0 * w4.w;
            a1[0] += v1 * w4.x; a1[1] += v1 * w4.y;
            a1[2] += v1 * w4.z; a1[3] += v1 * w4.w;
        }
#pragma unroll
        for (int jj = 0; jj < 4; ++jj) {
            int j = jc + jj;
            float bj = b1[j < WIDTH ? j : WIDTH - 1];
            float v0 = a0[jj] + bj;
            float v1 = a1[jj] + bj;
            h1t[rA * WPAD + j] = (j < WIDTH) ? (v0 > 0.f ? v0 : expm1f(v0)) : 0.f;
            h1t[rB * WPAD + j] = (j < WIDTH) ? (v1 > 0.f ? v1 : expm1f(v1)) : 0.f;
        }
    }
    lgkm_barrier();   // h1t ready; ALL W1 reads done -> wbuf reusable

    // ---- h2 with double-buffered W2; 2 rows x 4 cols per thread ----
    float a0[4] = {0.f, 0.f, 0.f, 0.f};
    float a1[4] = {0.f, 0.f, 0.f, 0.f};
    const float* h0 = h1t + rA * WPAD;
    const float* h1r = h1t + rB * WPAD;

#define STORE_CHUNK(BUFI, RV)                                   \
    _Pragma("unroll")                                           \
    for (int i = 0; i < 8; ++i)                                 \
        wbuf[(BUFI) * 4096 + i * 512 + tid] = RV[i];

#define LOAD_CHUNK(RV, K0)                                      \
    _Pragma("unroll")                                           \
    for (int i = 0; i < 8; ++i) {                               \
        int e = i * 512 + tid, kk = e >> 7, j = e & 127;        \
        int row = (K0) + kk;                                    \
        RV[i] = (j < WIDTH && row < WIDTH)                      \
                    ? W2[(size_t)row * WIDTH + j] : 0.f;        \
    }

#define COMPUTE_CHUNK(BUFI, K0)                                 \
    {                                                           \
        const float* wb = wbuf + (BUFI) * 4096;                 \
        _Pragma("unroll 4")                                     \
        for (int k = 0; k < 32; ++k) {                          \
            const float4 w4 = *(const float4*)(wb + k * WPAD + jc); \
            float v0 = h0[(K0) + k];                            \
            float v1 = h1r[(K0) + k];                           \
            a0[0] += v0 * w4.x; a0[1] += v0 * w4.y;             \
            a0[2] += v0 * w4.z; a0[3] += v0 * w4.w;             \
            a1[0] += v1 * w4.x; a1[1] += v1 * w4.y;             \
            a1[2] += v1 * w4.z; a1[3] += v1 * w4.w;             \
        }                                                       \
    }

    STORE_CHUNK(0, rvA);  LOAD_CHUNK(rvB, 32);
    lgkm_barrier();
    COMPUTE_CHUNK(0, 0);
    STORE_CHUNK(1, rvB);  LOAD_CHUNK(rvA, 64);
    lgkm_barrier();
    COMPUTE_CHUNK(1, 32);
    STORE_CHUNK(0, rvA);  LOAD_CHUNK(rvB, 96);
    lgkm_barrier();
    COMPUTE_CHUNK(0, 64);
    STORE_CHUNK(1, rvB);
    lgkm_barrier();
    COMPUTE_CHUNK(1, 96);

    // h2 = elu(acc+b2) in-register; fold out = h2@W3; width-32 shfl reduce
    {
        float pc0[NCLS] = {0.f, 0.f, 0.f, 0.f, 0.f, 0.f};
        float pc1[NCLS] = {0.f, 0.f, 0.f, 0.f, 0.f, 0.f};
#pragma unroll
        for (int jj = 0; jj < 4; ++jj) {
            int j = jc + jj;
            float bj = b2[j < WIDTH ? j : WIDTH - 1];
            float v0 = a0[jj] + bj;
            float v1 = a1[jj] + bj;
            float g0 = (j < WIDTH) ? (v0 > 0.f ? v0 : expm1f(v0)) : 0.f;
            float g1 = (j < WIDTH) ? (v1 > 0.f ? v1 : expm1f(v1)) : 0.f;
            const float* w3r = w3buf + j * NCLS;   // pad rows are 0
#pragma unroll
            for (int cc = 0; cc < NCLS; ++cc) {
                pc0[cc] += g0 * w3r[cc];
                pc1[cc] += g1 * w3r[cc];
            }
        }
#pragma unroll
        for (int mm = 1; mm < 32; mm <<= 1) {
#pragma unroll
            for (int cc = 0; cc < NCLS; ++cc) {
                pc0[cc] += __shfl_xor(pc0[cc], mm, 32);
                pc1[cc] += __shfl_xor(pc1[cc], mm, 32);
            }
        }
        if (cg == 0) {
#pragma unroll
            for (int cc = 0; cc < NCLS; ++cc) {
                out[(size_t)(row0 + rA) * NCLS + cc] = pc0[cc] + b3[cc];
                out[(size_t)(row0 + rB) * NCLS + cc] = pc1[cc] + b3[cc];
            }
        }
    }
#undef STORE_CHUNK
#undef LOAD_CHUNK
#undef COMPUTE_CHUNK
}

extern "C" void kernel_launch(void* const* d_in, const int* in_sizes, int n_in,
                              void* d_out, int out_size, void* d_ws, size_t ws_size,
                              hipStream_t stream) {
    const float* x     = (const float*)d_in[0];
    const int*   batch = (const int*)d_in[1];
    // Only conv index NCONV-1 == 1 affects the output (loop discards earlier)
    const float* Ws  = (const float*)d_in[2] + IN_F * SDIM;
    const float* bs  = (const float*)d_in[3] + SDIM;
    const float* Wh  = (const float*)d_in[4] + IN_F * PDIM;
    const float* bh  = (const float*)d_in[5] + PDIM;
    const float* Wo1 = (const float*)d_in[6] + IN_F * IN_F;
    const float* Wo2 = (const float*)d_in[7] + 2 * PDIM * IN_F;
    const float* bo2 = (const float*)d_in[8] + IN_F;
    const float* W1  = (const float*)d_in[9];
    const float* b1  = (const float*)d_in[10];
    const float* W2  = (const float*)d_in[11];
    const float* b2  = (const float*)d_in[12];
    const float* W3  = (const float*)d_in[13];
    const float* b3  = (const float*)d_in[14];
    float* out = (float*)d_out;

    char* ws = (char*)d_ws;
    int*   ranges = (int*)(ws + OFF_RANGES);
    float* S      = (float*)(ws + OFF_S);
    float* H      = (float*)(ws + OFF_H);
    int*   KIDX   = (int*)(ws + OFF_KIDX);
    float* KW     = (float*)(ws + OFF_KW);

    k_sh<<<dim3(NPT * 32 / 256), dim3(256), 0, stream>>>(x, batch, Ws, bs, Wh, bh, S, H, ranges);
    k_knn<<<dim3(NPT / 16), dim3(256), 0, stream>>>((const float4*)S, batch, ranges, KIDX, KW);
    k_fused<<<dim3(NPT / ROWS), dim3(512), 0, stream>>>(x, H, KIDX, KW, Wo1, Wo2, bo2,
                                                        W1, b1, W2, b2, W3, b3, out);
}